// Round 6
// baseline (218.909 us; speedup 1.0000x reference)
//
#include <hip/hip_runtime.h>

#define BT 32
#define CH 64
#define HS 56
#define WS 56
#define HH 28
#define WH 28

// ---------------- filter constants (exact reference values) ----------------
namespace {
constexpr float ISQ2 = 0.70710678118654752440f;
constexpr float F_H0[13] = {-0.0017578125f, 0.0f, 0.022265625f, -0.046875f,
    -0.0482421875f, 0.296875f, 0.55546875f, 0.296875f, -0.0482421875f,
    -0.046875f, 0.022265625f, 0.0f, -0.0017578125f};
constexpr float F_H1[19] = {-7.0626e-05f, 0.0f, 0.00134189f, -0.00188341f,
    -0.0071566f, 0.023856f, 0.0556431f, -0.0516881f, -0.299758f, 0.559431f,
    -0.299758f, -0.0516881f, 0.0556431f, 0.023856f, -0.0071566f,
    -0.00188341f, 0.00134189f, 0.0f, -7.0626e-05f};
constexpr float F_G0[19] = {7.0626e-05f, 0.0f, -0.00134189f, -0.00188341f,
    0.0071566f, 0.023856f, -0.0556431f, -0.0516881f, 0.299758f, 0.559431f,
    0.299758f, -0.0516881f, -0.0556431f, 0.023856f, 0.0071566f,
    -0.00188341f, -0.00134189f, 0.0f, 7.0626e-05f};
constexpr float F_G1[13] = {-0.0017578125f, 0.0f, 0.022265625f, 0.046875f,
    -0.0482421875f, -0.296875f, 0.55546875f, -0.296875f, -0.0482421875f,
    0.046875f, 0.022265625f, 0.0f, -0.0017578125f};
}

__device__ __forceinline__ int symi(int k) {
    k = (k < 0) ? (-1 - k) : k;
    k = (k >= HS) ? (2 * HS - 1 - k) : k;
    return k;
}

__device__ __forceinline__ unsigned short f2bf(float f) {  // RNE bf16
    unsigned u = __float_as_uint(f);
    u += 0x7fffu + ((u >> 16) & 1u);
    return (unsigned short)(u >> 16);
}
__device__ __forceinline__ float bf2f(unsigned short h) {
    return __uint_as_float(((unsigned)h) << 16);
}
// unpack 2 packed bf16 (channels c0, c0+1) from one dword
__device__ __forceinline__ float2 bfp2(unsigned u) {
    float2 r;
    r.x = __uint_as_float((u & 0xffffu) << 16);
    r.y = __uint_as_float(u & 0xffff0000u);
    return r;
}
__device__ __forceinline__ unsigned packbf(float a, float b) {
    return (unsigned)f2bf(a) | ((unsigned)f2bf(b) << 16);
}

typedef __attribute__((ext_vector_type(8))) short short8;  // 8 bf16 (4 VGPR)
typedef __attribute__((ext_vector_type(4))) float f32x4;

#define PPOS 784

// ---- K0: transpose w_ll [c][h][w] -> wllT [h][w][c] (staged in d_out head)
__global__ __launch_bounds__(256) void k_wll_T(const float* __restrict__ wll,
                                               float* __restrict__ wllT) {
    __shared__ float tile[64][65];
    int pos0 = blockIdx.x * 64;
    int lp = threadIdx.x & 63, g = threadIdx.x >> 6;
#pragma unroll
    for (int r = 0; r < 16; ++r) {
        int cc = r * 4 + g;
        tile[cc][lp] = wll[cc * (HS * WS) + pos0 + lp];
    }
    __syncthreads();
#pragma unroll
    for (int r = 0; r < 16; ++r) {
        int pl = r * 4 + g;
        wllT[(pos0 + pl) * CH + lp] = tile[lp][pl];
    }
}

// ---- K1: forward row filters: x -> lo, hi (bf16)
__global__ __launch_bounds__(256) void k_fwd_rows(const float* __restrict__ x,
                                                  unsigned short* __restrict__ lo,
                                                  unsigned short* __restrict__ hi) {
    int b = blockIdx.x / HS, h = blockIdx.x % HS;
    int strip = threadIdx.x >> 5;        // 0..7 strips of 7 w
    int c0 = (threadIdx.x & 31) * 2;
    int base = (b * HS + h) * WS * CH + c0;
    const float* row = x + base;
    unsigned short* lop = lo + base;
    unsigned short* hip = hi + base;
    int w0s = strip * 7;
    float Wa[19], Wb[19];
#pragma unroll
    for (int t = 0; t < 19; ++t) {
        float2 v = *(const float2*)(row + symi(w0s - 9 + t) * CH);
        Wa[t] = v.x; Wb[t] = v.y;
    }
    float2 nW[7];
#pragma unroll
    for (int u = 0; u < 7; ++u) nW[u] = *(const float2*)(row + symi(w0s + u + 10) * CH);
#pragma unroll
    for (int u = 0; u < 7; ++u) {
        int w = w0s + u;
        float aLo = 0.f, aHi = 0.f, bLo = 0.f, bHi = 0.f;
#pragma unroll
        for (int t = 0; t < 13; ++t) { aLo += F_H0[t] * Wa[3 + t]; bLo += F_H0[t] * Wb[3 + t]; }
#pragma unroll
        for (int t = 0; t < 19; ++t) { aHi += F_H1[t] * Wa[t]; bHi += F_H1[t] * Wb[t]; }
        *(unsigned*)(lop + w * CH) = packbf(aLo, bLo);
        *(unsigned*)(hip + w * CH) = packbf(aHi, bHi);
#pragma unroll
        for (int t = 0; t < 18; ++t) { Wa[t] = Wa[t + 1]; Wb[t] = Wb[t + 1]; }
        Wa[18] = nW[u].x; Wb[18] = nW[u].y;
    }
}

// ---- K2: FUSED column filters + q2c + MFMA channel mix -> xl, P0/P1/P2.
// Block = (b, wp, hf): filters both lo/hi sources for 14 ii, packs all 12
// q2c planes as bf16 into LDS pA, then runs the 2-layer MFMA mix in-block.
// sbT global tensor is eliminated.
__global__ __launch_bounds__(256) void k_cols_mix(
    const unsigned short* __restrict__ lo_in,
    const unsigned short* __restrict__ hi_in, const float* __restrict__ wllT,
    const float* __restrict__ w1, const float* __restrict__ w2,
    const float* __restrict__ b1, const float* __restrict__ b2,
    float* __restrict__ xl, unsigned short* __restrict__ P0,
    unsigned short* __restrict__ P1, unsigned short* __restrict__ P2) {
    // qT region (18432B) is dead after the last q2c; l1a/l1b alias it.
    __shared__ __align__(16) char smem0[2 * 4 * 64 * 9 * 4];
    __shared__ __align__(16) unsigned short pA[12][16][72];  // 27.6 KB
    float (*qT)[4][64][9] = (float(*)[4][64][9])smem0;
    unsigned short (*l1a)[16][36] = (unsigned short(*)[16][36])smem0;
    unsigned short (*l1b)[16][36] =
        (unsigned short(*)[16][36])(smem0 + 4 * 16 * 36 * 2);

    int hf = blockIdx.y;
    int b = blockIdx.x / WH, wp = blockIdx.x % WH;
    int w0 = 2 * wp, tid = threadIdx.x;
    int q = tid >> 6, c = tid & 63;
    int rp = q >> 1, jc = q & 1;
    int lane = tid & 63;
    int wv = tid >> 6;
    int quad = lane >> 4, n = lane & 15;
    int nb = __builtin_amdgcn_readfirstlane(wv);

    // ---- B-fragments + biases (loaded early; overlaps filter loads)
    short8 B1r, B1i, B2r, B2i;
#pragma unroll
    for (int j = 0; j < 8; ++j) {
        int kk = quad * 8 + j;
        int riw = kk >> 4, dd = kk & 15;
        float v1r = w1[nb * 256 + dd * 16 + n];
        float v1i = w1[1024 + nb * 256 + dd * 16 + n];
        float v2r = w2[nb * 256 + dd * 16 + n];
        float v2i = w2[1024 + nb * 256 + dd * 16 + n];
        B1r[j] = (short)f2bf(riw ? -v1i : v1r);
        B1i[j] = (short)f2bf(riw ? v1r : v1i);
        B2r[j] = (short)f2bf(riw ? -v2i : v2r);
        B2i[j] = (short)f2bf(riw ? v2r : v2i);
    }
    float bias1r = b1[nb * 16 + n], bias1i = b1[64 + nb * 16 + n];
    float bias2r = b2[nb * 16 + n], bias2i = b2[64 + nb * 16 + n];

    // ---- filter + q2c, both sources, 2 rounds of 7 ii each
    for (int src = 0; src < 2; ++src) {
        const unsigned short* srcp = src ? hi_in : lo_in;
        const unsigned short* colbase =
            srcp + (b * HS) * WS * CH + (w0 + jc) * CH + c;
        int hstart = 2 * (hf * 14) + rp;
        float W[19];
#pragma unroll
        for (int t = 0; t < 19; ++t)
            W[t] = bf2f(colbase[symi(hstart - 9 + t) * (WS * CH)]);
        float nW0[14], nW1[14], nwll[14];
#pragma unroll
        for (int u = 0; u < 14; ++u) {
            int h = hstart + 2 * u;
            nW0[u] = bf2f(colbase[symi(h + 10) * (WS * CH)]);
            nW1[u] = bf2f(colbase[symi(h + 11) * (WS * CH)]);
        }
        if (src == 0) {
#pragma unroll
            for (int u = 0; u < 14; ++u)
                nwll[u] = wllT[((hstart + 2 * u) * WS + (w0 + jc)) * CH + c];
        }
        for (int rnd = 0; rnd < 2; ++rnd) {
#pragma unroll
            for (int g = 0; g < 7; ++g) {
                int u = rnd * 7 + g;
                int h = hstart + 2 * u;
                float v0 = 0.f, v1 = 0.f;
#pragma unroll
                for (int t = 0; t < 13; ++t) v0 += F_H0[t] * W[3 + t];
#pragma unroll
                for (int t = 0; t < 19; ++t) v1 += F_H1[t] * W[t];
                if (src == 0) {
                    xl[((b * HS + h) * WS + (w0 + jc)) * CH + c] = v0 * nwll[u];
                    qT[0][q][c][g] = v1;
                } else {
                    qT[0][q][c][g] = v0;   // hl
                    qT[1][q][c][g] = v1;   // hh
                }
#pragma unroll
                for (int t = 0; t < 17; ++t) W[t] = W[t + 2];
                W[17] = nW0[u];
                W[18] = nW1[u];
            }
            __syncthreads();
            // q2c + bf16 pack into pA (this round's 7 ii)
            {
                int qq = tid >> 5;
                int role = qq & 3, sub = qq >> 2;
                int c0 = (tid & 31) * 2;
                int rowA = role & 1, rowB = 3 - (role & 1);
                float sgn = (role == 1 || role == 2) ? 1.f : -1.f;
                int iL = sub ? 4 : 0, iH = sub ? 7 : 4;
                if (src == 0) {
                    int p = (role < 2) ? role : role + 8;  // 0,1,10,11
                    for (int ii = iL; ii < iH; ++ii) {
                        float v0 = (qT[0][rowA][c0][ii] + sgn * qT[0][rowB][c0][ii]) * ISQ2;
                        float v1 = (qT[0][rowA][c0 + 1][ii] + sgn * qT[0][rowB][c0 + 1][ii]) * ISQ2;
                        *(unsigned*)&pA[p][rnd * 7 + ii][c0] = packbf(v0, v1);
                    }
                } else {
#pragma unroll
                    for (int s2 = 0; s2 < 2; ++s2) {
                        // s2=0 (hl): planes 4..7; s2=1 (hh): planes 2,3,8,9
                        int p = (s2 == 0) ? (4 + role)
                                          : ((role < 2) ? (2 + role) : (6 + role));
                        for (int ii = iL; ii < iH; ++ii) {
                            float v0 = (qT[s2][rowA][c0][ii] + sgn * qT[s2][rowB][c0][ii]) * ISQ2;
                            float v1 = (qT[s2][rowA][c0 + 1][ii] + sgn * qT[s2][rowB][c0 + 1][ii]) * ISQ2;
                            *(unsigned*)&pA[p][rnd * 7 + ii][c0] = packbf(v0, v1);
                        }
                    }
                }
            }
            __syncthreads();
        }
    }
    // pA complete; qT dead (l1a/l1b alias it). No further block-wide barriers
    // needed: l1 exchange is intra-wave ([wv] slices), pA is read-only.

    // ---- mix phase: 3 plane-pair products, M-rows = 14 local positions
    int rix = quad >> 1, dlo = (quad & 1) * 8;
    int chb = nb * 16 + dlo;
#pragma unroll
    for (int pr = 0; pr < 3; ++pr) {
        const int sa = (pr == 0) ? 0 : (pr == 1) ? 2 : 1;
        const int sb = (pr == 0) ? 5 : (pr == 1) ? 3 : 4;
        unsigned short* Pd = (pr == 0) ? P0 : (pr == 1) ? P1 : P2;
        short8 A1a = *(const short8*)&pA[sa * 2 + rix][n][chb];
        short8 A1b = *(const short8*)&pA[sb * 2 + rix][n][chb];
        f32x4 a1r = {bias1r, bias1r, bias1r, bias1r};
        f32x4 a1i = {bias1i, bias1i, bias1i, bias1i};
        f32x4 b1r_ = a1r, b1i_ = a1i;
        a1r = __builtin_amdgcn_mfma_f32_16x16x32_bf16(A1a, B1r, a1r, 0, 0, 0);
        a1i = __builtin_amdgcn_mfma_f32_16x16x32_bf16(A1a, B1i, a1i, 0, 0, 0);
        b1r_ = __builtin_amdgcn_mfma_f32_16x16x32_bf16(A1b, B1r, b1r_, 0, 0, 0);
        b1i_ = __builtin_amdgcn_mfma_f32_16x16x32_bf16(A1b, B1i, b1i_, 0, 0, 0);
#pragma unroll
        for (int r = 0; r < 4; ++r) {
            int pos = quad * 4 + r;
            l1a[wv][pos][n] = f2bf(fmaxf(a1r[r], 0.f));
            l1a[wv][pos][16 + n] = f2bf(fmaxf(a1i[r], 0.f));
            l1b[wv][pos][n] = f2bf(fmaxf(b1r_[r], 0.f));
            l1b[wv][pos][16 + n] = f2bf(fmaxf(b1i_[r], 0.f));
        }
        union { short8 s8; uint2 u2[2]; } a2a, a2b;
        const unsigned short* rowpa = &l1a[wv][n][0];
        const unsigned short* rowpb = &l1b[wv][n][0];
        a2a.u2[0] = *(const uint2*)(rowpa + quad * 8);
        a2a.u2[1] = *(const uint2*)(rowpa + quad * 8 + 4);
        a2b.u2[0] = *(const uint2*)(rowpb + quad * 8);
        a2b.u2[1] = *(const uint2*)(rowpb + quad * 8 + 4);
        f32x4 aAr = {bias2r, bias2r, bias2r, bias2r};
        f32x4 aAi = {bias2i, bias2i, bias2i, bias2i};
        f32x4 aBr = aAr, aBi = aAi;
        aAr = __builtin_amdgcn_mfma_f32_16x16x32_bf16(a2a.s8, B2r, aAr, 0, 0, 0);
        aAi = __builtin_amdgcn_mfma_f32_16x16x32_bf16(a2a.s8, B2i, aAi, 0, 0, 0);
        aBr = __builtin_amdgcn_mfma_f32_16x16x32_bf16(a2b.s8, B2r, aBr, 0, 0, 0);
        aBi = __builtin_amdgcn_mfma_f32_16x16x32_bf16(a2b.s8, B2i, aBi, 0, 0, 0);
#pragma unroll
        for (int r = 0; r < 4; ++r) {
            int m = quad * 4 + r;
            if (m < 14) {
                int iimg = hf * 14 + m;
                int o = ((b * HS + 2 * iimg) * WS + 2 * wp) * CH + nb * 16 + n;
                Pd[o] = f2bf((aAr[r] + aBr[r]) * ISQ2);
                Pd[o + CH] = f2bf((aAi[r] + aBi[r]) * ISQ2);
                Pd[o + WS * CH] = f2bf((aAi[r] - aBi[r]) * ISQ2);
                Pd[o + WS * CH + CH] = f2bf((aBr[r] - aAr[r]) * ISQ2);
            }
        }
    }
}

// ---- K4: inverse column pass, templated on mode (uniform blockIdx.z):
//   MODE=0: lo2 = G0col(xl fp32) + G1col(P0);  MODE=1: hi2 = G0col(P1) + G1col(P2)
// hf=2 halves (28 outputs); 2ch/thread; 2-deep software-pipelined groups of 4.
template <int MODE>
__device__ __forceinline__ void inv_cols_body(
    const float* __restrict__ xl, const unsigned short* __restrict__ P0,
    const unsigned short* __restrict__ P1, const unsigned short* __restrict__ P2,
    float* __restrict__ lo2, float* __restrict__ hi2) {
    int hf = blockIdx.y;
    int b = blockIdx.x / 7, wg = blockIdx.x % 7;
    int wl = threadIdx.x >> 5, l = threadIdx.x & 31;
    int c0 = l * 2;
    int w = wg * 8 + wl;
    int base = (b * HS) * WS * CH + w * CH + c0;
    const int st = WS * CH;
    const unsigned short* Bp = (MODE == 0) ? P0 : P2;
    float* outp = (MODE == 0) ? lo2 : hi2;
    auto ldA = [&](int r) -> float2 {
        if (MODE == 0) return *(const float2*)(xl + base + r * st);
        return bfp2(*(const unsigned*)(P1 + base + r * st));
    };
    auto ldB = [&](int r) -> float2 {
        return bfp2(*(const unsigned*)(Bp + base + r * st));
    };
    int h0 = hf * 28;
    float Aa[19], Ab[19], Ba[13], Bb[13];
#pragma unroll
    for (int t = 0; t < 19; ++t) { float2 v = ldA(symi(h0 - 9 + t)); Aa[t] = v.x; Ab[t] = v.y; }
#pragma unroll
    for (int t = 0; t < 13; ++t) { float2 v = ldB(symi(h0 - 6 + t)); Ba[t] = v.x; Bb[t] = v.y; }
    float2 pa0[4], pb0[4], pa1[4], pb1[4];
#define LDG(bA, bB, G)                                                          \
    {                                                                           \
        _Pragma("unroll") for (int u = 0; u < 4; ++u)                           \
            bA[u] = ldA(symi(h0 + (G) * 4 + u + 10));                           \
        _Pragma("unroll") for (int u = 0; u < 4; ++u)                           \
            bB[u] = ldB(symi(h0 + (G) * 4 + u + 7));                            \
    }
#define CPG(bA, bB, G)                                                          \
    {                                                                           \
        _Pragma("unroll") for (int u = 0; u < 4; ++u) {                         \
            int h = h0 + (G) * 4 + u;                                           \
            float acca = 0.f, accb = 0.f;                                       \
            _Pragma("unroll") for (int t = 0; t < 19; ++t) {                    \
                acca += F_G0[t] * Aa[t]; accb += F_G0[t] * Ab[t];               \
            }                                                                   \
            _Pragma("unroll") for (int t = 0; t < 13; ++t) {                    \
                acca += F_G1[t] * Ba[t]; accb += F_G1[t] * Bb[t];               \
            }                                                                   \
            float2 ov; ov.x = acca; ov.y = accb;                                \
            *(float2*)(outp + base + h * st) = ov;                              \
            _Pragma("unroll") for (int t = 0; t < 18; ++t) {                    \
                Aa[t] = Aa[t + 1]; Ab[t] = Ab[t + 1];                           \
            }                                                                   \
            _Pragma("unroll") for (int t = 0; t < 12; ++t) {                    \
                Ba[t] = Ba[t + 1]; Bb[t] = Bb[t + 1];                           \
            }                                                                   \
            Aa[18] = bA[u].x; Ab[18] = bA[u].y;                                 \
            Ba[12] = bB[u].x; Bb[12] = bB[u].y;                                 \
        }                                                                       \
    }
    LDG(pa0, pb0, 0) LDG(pa1, pb1, 1)
    CPG(pa0, pb0, 0) LDG(pa0, pb0, 2)
    CPG(pa1, pb1, 1) LDG(pa1, pb1, 3)
    CPG(pa0, pb0, 2) LDG(pa0, pb0, 4)
    CPG(pa1, pb1, 3) LDG(pa1, pb1, 5)
    CPG(pa0, pb0, 4) LDG(pa0, pb0, 6)
    CPG(pa1, pb1, 5)
    CPG(pa0, pb0, 6)
#undef LDG
#undef CPG
}

__global__ __launch_bounds__(256) void k_inv_cols(
    const float* __restrict__ xl, const unsigned short* __restrict__ P0,
    const unsigned short* __restrict__ P1, const unsigned short* __restrict__ P2,
    float* __restrict__ lo2, float* __restrict__ hi2) {
    if (blockIdx.z == 0)
        inv_cols_body<0>(xl, P0, P1, P2, lo2, hi2);
    else
        inv_cols_body<1>(xl, P0, P1, P2, lo2, hi2);
}

// ---- K5: inverse row filters -> out (fp32), 2 channels/thread, batched
__global__ __launch_bounds__(256) void k_inv_rows(const float* __restrict__ lo2,
                                                  const float* __restrict__ hi2,
                                                  float* __restrict__ out) {
    int b = blockIdx.x / HS, h = blockIdx.x % HS;
    int strip = threadIdx.x >> 5;        // 0..7 strips of 7 w
    int c0 = (threadIdx.x & 31) * 2;
    int base = (b * HS + h) * WS * CH + c0;
    const float* rlo = lo2 + base;
    const float* rhi = hi2 + base;
    float* op = out + base;
    int w0s = strip * 7;
    float Aa[19], Ab[19], Ba[13], Bb[13];
#pragma unroll
    for (int t = 0; t < 19; ++t) {
        float2 v = *(const float2*)(rlo + symi(w0s - 9 + t) * CH);
        Aa[t] = v.x; Ab[t] = v.y;
    }
#pragma unroll
    for (int t = 0; t < 13; ++t) {
        float2 v = *(const float2*)(rhi + symi(w0s - 6 + t) * CH);
        Ba[t] = v.x; Bb[t] = v.y;
    }
    float2 nA[7], nB[7];
#pragma unroll
    for (int u = 0; u < 7; ++u) nA[u] = *(const float2*)(rlo + symi(w0s + u + 10) * CH);
#pragma unroll
    for (int u = 0; u < 7; ++u) nB[u] = *(const float2*)(rhi + symi(w0s + u + 7) * CH);
#pragma unroll
    for (int u = 0; u < 7; ++u) {
        int w = w0s + u;
        float acca = 0.f, accb = 0.f;
#pragma unroll
        for (int t = 0; t < 19; ++t) { acca += F_G0[t] * Aa[t]; accb += F_G0[t] * Ab[t]; }
#pragma unroll
        for (int t = 0; t < 13; ++t) { acca += F_G1[t] * Ba[t]; accb += F_G1[t] * Bb[t]; }
        float2 ov; ov.x = acca; ov.y = accb;
        *(float2*)(op + w * CH) = ov;
#pragma unroll
        for (int t = 0; t < 18; ++t) { Aa[t] = Aa[t + 1]; Ab[t] = Ab[t + 1]; }
#pragma unroll
        for (int t = 0; t < 12; ++t) { Ba[t] = Ba[t + 1]; Bb[t] = Bb[t + 1]; }
        Aa[18] = nA[u].x; Ab[18] = nA[u].y;
        Ba[12] = nB[u].x; Bb[12] = nB[u].y;
    }
}

extern "C" void kernel_launch(void* const* d_in, const int* in_sizes, int n_in,
                              void* d_out, int out_size, void* d_ws, size_t ws_size,
                              hipStream_t stream) {
    const float* x = (const float*)d_in[0];
    const float* w_ll = (const float*)d_in[1];
    const float* w1 = (const float*)d_in[2];
    const float* w2 = (const float*)d_in[3];
    const float* b1 = (const float*)d_in[4];
    const float* b2 = (const float*)d_in[5];
    float* out = (float*)d_out;

    // workspace map (float units), addresses unchanged from round 5 (the old
    // sbT region now only hosts lo2):
    // xl | lo2(region SBf) | hi2 | lo_in | hi_in | P0 | P1 | P2
    const size_t A = (size_t)BT * HS * WS * CH;
    const size_t SBf = (size_t)12 * 64 * BT * PPOS / 2;
    float* wsf = (float*)d_ws;
    float* xl = wsf;                                    // fp32, read by inv mode0
    float* lo2 = wsf + A;
    float* hi2 = wsf + A + SBf;                         // fp32 (no alias w/ xl!)
    unsigned short* lo_in = (unsigned short*)(wsf + A + SBf + A);
    unsigned short* hi_in = lo_in + A;                  // bf16
    unsigned short* P0 = hi_in + A;                     // bf16
    unsigned short* P1 = P0 + A;
    unsigned short* P2 = P1 + A;

    float* wllT = out;  // staged in d_out head (overwritten by k_inv_rows)

    k_wll_T<<<49, 256, 0, stream>>>(w_ll, wllT);
    k_fwd_rows<<<BT * HS, 256, 0, stream>>>(x, lo_in, hi_in);
    k_cols_mix<<<dim3(BT * WH, 2), 256, 0, stream>>>(lo_in, hi_in, wllT, w1, w2,
                                                     b1, b2, xl, P0, P1, P2);
    k_inv_cols<<<dim3(BT * 7, 2, 2), 256, 0, stream>>>(xl, P0, P1, P2, lo2, hi2);
    k_inv_rows<<<BT * HS, 256, 0, stream>>>(lo2, hi2, out);
}

// Round 7
// 172.965 us; speedup vs baseline: 1.2656x; 1.2656x over previous
//
#include <hip/hip_runtime.h>

#define BT 32
#define CH 64
#define HS 56
#define WS 56
#define HH 28
#define WH 28

// ---------------- filter constants (exact reference values) ----------------
namespace {
constexpr float ISQ2 = 0.70710678118654752440f;
constexpr float F_H0[13] = {-0.0017578125f, 0.0f, 0.022265625f, -0.046875f,
    -0.0482421875f, 0.296875f, 0.55546875f, 0.296875f, -0.0482421875f,
    -0.046875f, 0.022265625f, 0.0f, -0.0017578125f};
constexpr float F_H1[19] = {-7.0626e-05f, 0.0f, 0.00134189f, -0.00188341f,
    -0.0071566f, 0.023856f, 0.0556431f, -0.0516881f, -0.299758f, 0.559431f,
    -0.299758f, -0.0516881f, 0.0556431f, 0.023856f, -0.0071566f,
    -0.00188341f, 0.00134189f, 0.0f, -7.0626e-05f};
constexpr float F_G0[19] = {7.0626e-05f, 0.0f, -0.00134189f, -0.00188341f,
    0.0071566f, 0.023856f, -0.0556431f, -0.0516881f, 0.299758f, 0.559431f,
    0.299758f, -0.0516881f, -0.0556431f, 0.023856f, 0.0071566f,
    -0.00188341f, -0.00134189f, 0.0f, 7.0626e-05f};
constexpr float F_G1[13] = {-0.0017578125f, 0.0f, 0.022265625f, 0.046875f,
    -0.0482421875f, -0.296875f, 0.55546875f, -0.296875f, -0.0482421875f,
    0.046875f, 0.022265625f, 0.0f, -0.0017578125f};
}

__device__ __forceinline__ int symi(int k) {
    k = (k < 0) ? (-1 - k) : k;
    k = (k >= HS) ? (2 * HS - 1 - k) : k;
    return k;
}

__device__ __forceinline__ unsigned short f2bf(float f) {  // RNE bf16
    unsigned u = __float_as_uint(f);
    u += 0x7fffu + ((u >> 16) & 1u);
    return (unsigned short)(u >> 16);
}
__device__ __forceinline__ float bf2f(unsigned short h) {
    return __uint_as_float(((unsigned)h) << 16);
}
// unpack 2 packed bf16 (channels c0, c0+1) from one dword
__device__ __forceinline__ float2 bfp2(unsigned u) {
    float2 r;
    r.x = __uint_as_float((u & 0xffffu) << 16);
    r.y = __uint_as_float(u & 0xffff0000u);
    return r;
}
__device__ __forceinline__ unsigned packbf(float a, float b) {
    return (unsigned)f2bf(a) | ((unsigned)f2bf(b) << 16);
}

typedef __attribute__((ext_vector_type(8))) short short8;  // 8 bf16 (4 VGPR)
typedef __attribute__((ext_vector_type(4))) float f32x4;

// sbT layout: [p 12][b 32][pos 784][c 64], bf16.
#define PPOS 784

// ---- K1: forward row filters: x -> lo, hi (bf16).
// Blocks 0..48 additionally transpose w_ll -> wllT (folds old k_wll_T launch).
__global__ __launch_bounds__(256) void k_fwd_rows(const float* __restrict__ x,
                                                  unsigned short* __restrict__ lo,
                                                  unsigned short* __restrict__ hi,
                                                  const float* __restrict__ wll,
                                                  float* __restrict__ wllT) {
    int b = blockIdx.x / HS, h = blockIdx.x % HS;
    int strip = threadIdx.x >> 5;        // 0..7 strips of 7 w
    int c0 = (threadIdx.x & 31) * 2;
    int base = (b * HS + h) * WS * CH + c0;
    const float* row = x + base;
    unsigned short* lop = lo + base;
    unsigned short* hip = hi + base;
    int w0s = strip * 7;
    float Wa[19], Wb[19];
#pragma unroll
    for (int t = 0; t < 19; ++t) {
        float2 v = *(const float2*)(row + symi(w0s - 9 + t) * CH);
        Wa[t] = v.x; Wb[t] = v.y;
    }
    float2 nW[7];
#pragma unroll
    for (int u = 0; u < 7; ++u) nW[u] = *(const float2*)(row + symi(w0s + u + 10) * CH);
#pragma unroll
    for (int u = 0; u < 7; ++u) {
        int w = w0s + u;
        float aLo = 0.f, aHi = 0.f, bLo = 0.f, bHi = 0.f;
#pragma unroll
        for (int t = 0; t < 13; ++t) { aLo += F_H0[t] * Wa[3 + t]; bLo += F_H0[t] * Wb[3 + t]; }
#pragma unroll
        for (int t = 0; t < 19; ++t) { aHi += F_H1[t] * Wa[t]; bHi += F_H1[t] * Wb[t]; }
        *(unsigned*)(lop + w * CH) = packbf(aLo, bLo);
        *(unsigned*)(hip + w * CH) = packbf(aHi, bHi);
#pragma unroll
        for (int t = 0; t < 18; ++t) { Wa[t] = Wa[t + 1]; Wb[t] = Wb[t + 1]; }
        Wa[18] = nW[u].x; Wb[18] = nW[u].y;
    }
    // ---- folded w_ll transpose (uniform per-block branch; 49 blocks) ----
    if (blockIdx.x < 49) {
        __shared__ float tile[64][65];
        int pos0 = blockIdx.x * 64;
        int lp = threadIdx.x & 63, g = threadIdx.x >> 6;
#pragma unroll
        for (int r = 0; r < 16; ++r) {
            int cc = r * 4 + g;
            tile[cc][lp] = wll[cc * (HS * WS) + pos0 + lp];
        }
        __syncthreads();
#pragma unroll
        for (int r = 0; r < 16; ++r) {
            int pl = r * 4 + g;
            wllT[(pos0 + pl) * CH + lp] = tile[lp][pl];
        }
    }
}

// ---- K2: merged column filters (z=0: lo path, z=1: hi path), hf=2 halves.
__global__ __launch_bounds__(256) void k_cols(
    const unsigned short* __restrict__ lo_in,
    const unsigned short* __restrict__ hi_in, const float* __restrict__ wllT,
    float* __restrict__ xl, unsigned short* __restrict__ sbT) {
    __shared__ float qT[2][4][64][15];  // 30.7 KB; lo path uses qT[0] only
    int hf = blockIdx.y;
    int zmode = blockIdx.z;            // uniform branch
    int b = blockIdx.x / WH, wp = blockIdx.x % WH;
    int w0 = 2 * wp, tid = threadIdx.x;
    int q = tid >> 6, c = tid & 63;
    int rp = q >> 1, jc = q & 1;
    const unsigned short* srcp = zmode ? hi_in : lo_in;
    const unsigned short* colbase = srcp + (b * HS) * WS * CH + (w0 + jc) * CH + c;
    {
        int hstart = 2 * (hf * 14) + rp;
        float W[19];
#pragma unroll
        for (int t = 0; t < 19; ++t) W[t] = bf2f(colbase[symi(hstart - 9 + t) * (WS * CH)]);
        float nW0[14], nW1[14], nwll[14];
#pragma unroll
        for (int u = 0; u < 14; ++u) {
            int h = hstart + 2 * u;
            nW0[u] = bf2f(colbase[symi(h + 10) * (WS * CH)]);
            nW1[u] = bf2f(colbase[symi(h + 11) * (WS * CH)]);
        }
        if (zmode == 0) {
#pragma unroll
            for (int u = 0; u < 14; ++u)
                nwll[u] = wllT[((hstart + 2 * u) * WS + (w0 + jc)) * CH + c];
        }
#pragma unroll
        for (int u = 0; u < 14; ++u) {
            int h = hstart + 2 * u;
            float v0 = 0.f, v1 = 0.f;
#pragma unroll
            for (int t = 0; t < 13; ++t) v0 += F_H0[t] * W[3 + t];
#pragma unroll
            for (int t = 0; t < 19; ++t) v1 += F_H1[t] * W[t];
            if (zmode == 0) {
                xl[((b * HS + h) * WS + (w0 + jc)) * CH + c] = v0 * nwll[u];
                qT[0][q][c][u] = v1;
            } else {
                qT[0][q][c][u] = v0;   // hl
                qT[1][q][c][u] = v1;   // hh
            }
#pragma unroll
            for (int t = 0; t < 17; ++t) W[t] = W[t + 2];
            W[17] = nW0[u];
            W[18] = nW1[u];
        }
    }
    __syncthreads();
    // fused q2c + bf16 pack: role 0:(a-d) 1:(b+c) 2:(a+d) 3:(b-c)
    {
        int qq = tid >> 5;                 // 0..7
        int role = qq & 3, half = qq >> 2; // ii 0..6 / 7..13
        int c0 = (tid & 31) * 2;
        int rowA = role & 1, rowB = 3 - (role & 1);
        float sgn = (role == 1 || role == 2) ? 1.f : -1.f;
        int posb = wp * 28 + hf * 14;
        if (zmode == 0) {
            int p = (role < 2) ? role : role + 8;  // planes 0,1,10,11
            const float* qA0 = &qT[0][rowA][c0][0];
            const float* qA1 = &qT[0][rowA][c0 + 1][0];
            const float* qB0 = &qT[0][rowB][c0][0];
            const float* qB1 = &qT[0][rowB][c0 + 1][0];
            unsigned short* dst = sbT + ((p * BT + b) * PPOS + posb) * CH + c0;
#pragma unroll
            for (int g = 0; g < 7; ++g) {
                int ii = half * 7 + g;
                float v0 = (qA0[ii] + sgn * qB0[ii]) * ISQ2;
                float v1 = (qA1[ii] + sgn * qB1[ii]) * ISQ2;
                *(unsigned*)(dst + ii * CH) = packbf(v0, v1);
            }
        } else {
#pragma unroll
            for (int src = 0; src < 2; ++src) {
                // src0 (hl): planes 4..7; src1 (hh): planes 2,3,8,9
                int p = (src == 0) ? (4 + role) : ((role < 2) ? (2 + role) : (6 + role));
                const float* qA0 = &qT[src][rowA][c0][0];
                const float* qA1 = &qT[src][rowA][c0 + 1][0];
                const float* qB0 = &qT[src][rowB][c0][0];
                const float* qB1 = &qT[src][rowB][c0 + 1][0];
                unsigned short* dst = sbT + ((p * BT + b) * PPOS + posb) * CH + c0;
#pragma unroll
                for (int g = 0; g < 7; ++g) {
                    int ii = half * 7 + g;
                    float v0 = (qA0[ii] + sgn * qB0[ii]) * ISQ2;
                    float v1 = (qA1[ii] + sgn * qB1[ii]) * ISQ2;
                    *(unsigned*)(dst + ii * CH) = packbf(v0, v1);
                }
            }
        }
    }
}

// ---- K3: MFMA channel mixing + fused c2q -> bf16 planes P[b][h][w][c]
// 4-wave blocks (wv = nb); A-fragments register double-buffered across t.
__global__ __launch_bounds__(256) void k_mix(
    const unsigned short* __restrict__ sbT, const float* __restrict__ w1,
    const float* __restrict__ w2, const float* __restrict__ b1,
    const float* __restrict__ b2, unsigned short* __restrict__ P0,
    unsigned short* __restrict__ P1, unsigned short* __restrict__ P2) {
    __shared__ unsigned short l1a[4][16][36];
    __shared__ unsigned short l1b[4][16][36];
    int blk = blockIdx.x;
    int pr = blk / (BT * 7);
    int rem = blk % (BT * 7);
    int b = rem / 7;
    int chunk = rem % 7;
    int sa = (pr == 0) ? 0 : (pr == 1) ? 2 : 1;
    int sb = (pr == 0) ? 5 : (pr == 1) ? 3 : 4;
    unsigned short* Pd = (pr == 0) ? P0 : (pr == 1) ? P1 : P2;
    int tid = threadIdx.x;
    int lane = tid & 63;
    int wv = tid >> 6;
    int nb = __builtin_amdgcn_readfirstlane(wv);
    int quad = lane >> 4;
    int n = lane & 15;

    short8 B1r, B1i, B2r, B2i;
#pragma unroll
    for (int j = 0; j < 8; ++j) {
        int kk = quad * 8 + j;
        int riw = kk >> 4, dd = kk & 15;
        float v1r = w1[nb * 256 + dd * 16 + n];
        float v1i = w1[1024 + nb * 256 + dd * 16 + n];
        float v2r = w2[nb * 256 + dd * 16 + n];
        float v2i = w2[1024 + nb * 256 + dd * 16 + n];
        B1r[j] = (short)f2bf(riw ? -v1i : v1r);
        B1i[j] = (short)f2bf(riw ? v1r : v1i);
        B2r[j] = (short)f2bf(riw ? -v2i : v2r);
        B2i[j] = (short)f2bf(riw ? v2r : v2i);
    }
    float bias1r = b1[nb * 16 + n], bias1i = b1[64 + nb * 16 + n];
    float bias2r = b2[nb * 16 + n], bias2i = b2[64 + nb * 16 + n];

    int rix = quad >> 1, dlo = (quad & 1) * 8;
    const unsigned short* pAa =
        sbT + (((sa * 2 + rix) * BT + b) * PPOS + n) * CH + nb * 16 + dlo;
    const unsigned short* pAb =
        sbT + (((sb * 2 + rix) * BT + b) * PPOS + n) * CH + nb * 16 + dlo;

    int pbase = chunk * 112;
    short8 A1a = *(const short8*)(pAa + pbase * CH);
    short8 A1b = *(const short8*)(pAb + pbase * CH);
    for (int t = 0; t < 7; ++t) {
        int pos0 = pbase + t * 16;
        short8 nAa = A1a, nAb = A1b;
        if (t < 6) {
            nAa = *(const short8*)(pAa + (pos0 + 16) * CH);
            nAb = *(const short8*)(pAb + (pos0 + 16) * CH);
        }
        f32x4 a1r = {bias1r, bias1r, bias1r, bias1r};
        f32x4 a1i = {bias1i, bias1i, bias1i, bias1i};
        f32x4 b1r_ = a1r, b1i_ = a1i;
        a1r = __builtin_amdgcn_mfma_f32_16x16x32_bf16(A1a, B1r, a1r, 0, 0, 0);
        a1i = __builtin_amdgcn_mfma_f32_16x16x32_bf16(A1a, B1i, a1i, 0, 0, 0);
        b1r_ = __builtin_amdgcn_mfma_f32_16x16x32_bf16(A1b, B1r, b1r_, 0, 0, 0);
        b1i_ = __builtin_amdgcn_mfma_f32_16x16x32_bf16(A1b, B1i, b1i_, 0, 0, 0);
#pragma unroll
        for (int r = 0; r < 4; ++r) {
            int pos = quad * 4 + r;
            l1a[wv][pos][n] = f2bf(fmaxf(a1r[r], 0.f));
            l1a[wv][pos][16 + n] = f2bf(fmaxf(a1i[r], 0.f));
            l1b[wv][pos][n] = f2bf(fmaxf(b1r_[r], 0.f));
            l1b[wv][pos][16 + n] = f2bf(fmaxf(b1i_[r], 0.f));
        }
        union { short8 s8; uint2 u2[2]; } a2a, a2b;
        const unsigned short* rowpa = &l1a[wv][n][0];
        const unsigned short* rowpb = &l1b[wv][n][0];
        a2a.u2[0] = *(const uint2*)(rowpa + quad * 8);
        a2a.u2[1] = *(const uint2*)(rowpa + quad * 8 + 4);
        a2b.u2[0] = *(const uint2*)(rowpb + quad * 8);
        a2b.u2[1] = *(const uint2*)(rowpb + quad * 8 + 4);
        f32x4 aAr = {bias2r, bias2r, bias2r, bias2r};
        f32x4 aAi = {bias2i, bias2i, bias2i, bias2i};
        f32x4 aBr = aAr, aBi = aAi;
        aAr = __builtin_amdgcn_mfma_f32_16x16x32_bf16(a2a.s8, B2r, aAr, 0, 0, 0);
        aAi = __builtin_amdgcn_mfma_f32_16x16x32_bf16(a2a.s8, B2i, aAi, 0, 0, 0);
        aBr = __builtin_amdgcn_mfma_f32_16x16x32_bf16(a2b.s8, B2r, aBr, 0, 0, 0);
        aBi = __builtin_amdgcn_mfma_f32_16x16x32_bf16(a2b.s8, B2i, aBi, 0, 0, 0);
#pragma unroll
        for (int r = 0; r < 4; ++r) {
            int pos_g = pos0 + quad * 4 + r;
            int wp = pos_g / 28, ii = pos_g - wp * 28;
            int o = ((b * HS + 2 * ii) * WS + 2 * wp) * CH + nb * 16 + n;
            Pd[o] = f2bf((aAr[r] + aBr[r]) * ISQ2);
            Pd[o + CH] = f2bf((aAi[r] + aBi[r]) * ISQ2);
            Pd[o + WS * CH] = f2bf((aAi[r] - aBi[r]) * ISQ2);
            Pd[o + WS * CH + CH] = f2bf((aBr[r] - aAr[r]) * ISQ2);
        }
        A1a = nAa; A1b = nAb;
    }
}

// ---- K4: inverse column pass, templated on mode (uniform blockIdx.z):
//   MODE=0: lo2 = G0col(xl fp32) + G1col(P0);  MODE=1: hi2 = G0col(P1) + G1col(P2)
// Outputs lo2/hi2 now bf16 (packed-uint stores). 2-deep pipelined groups of 4.
template <int MODE>
__device__ __forceinline__ void inv_cols_body(
    const float* __restrict__ xl, const unsigned short* __restrict__ P0,
    const unsigned short* __restrict__ P1, const unsigned short* __restrict__ P2,
    unsigned short* __restrict__ lo2, unsigned short* __restrict__ hi2) {
    int hf = blockIdx.y;
    int b = blockIdx.x / 7, wg = blockIdx.x % 7;
    int wl = threadIdx.x >> 5, l = threadIdx.x & 31;
    int c0 = l * 2;
    int w = wg * 8 + wl;
    int base = (b * HS) * WS * CH + w * CH + c0;
    const int st = WS * CH;
    const unsigned short* Bp = (MODE == 0) ? P0 : P2;
    unsigned short* outp = (MODE == 0) ? lo2 : hi2;
    auto ldA = [&](int r) -> float2 {
        if (MODE == 0) return *(const float2*)(xl + base + r * st);
        return bfp2(*(const unsigned*)(P1 + base + r * st));
    };
    auto ldB = [&](int r) -> float2 {
        return bfp2(*(const unsigned*)(Bp + base + r * st));
    };
    int h0 = hf * 28;
    float Aa[19], Ab[19], Ba[13], Bb[13];
#pragma unroll
    for (int t = 0; t < 19; ++t) { float2 v = ldA(symi(h0 - 9 + t)); Aa[t] = v.x; Ab[t] = v.y; }
#pragma unroll
    for (int t = 0; t < 13; ++t) { float2 v = ldB(symi(h0 - 6 + t)); Ba[t] = v.x; Bb[t] = v.y; }
    float2 pa0[4], pb0[4], pa1[4], pb1[4];
#define LDG(bA, bB, G)                                                          \
    {                                                                           \
        _Pragma("unroll") for (int u = 0; u < 4; ++u)                           \
            bA[u] = ldA(symi(h0 + (G) * 4 + u + 10));                           \
        _Pragma("unroll") for (int u = 0; u < 4; ++u)                           \
            bB[u] = ldB(symi(h0 + (G) * 4 + u + 7));                            \
    }
#define CPG(bA, bB, G)                                                          \
    {                                                                           \
        _Pragma("unroll") for (int u = 0; u < 4; ++u) {                         \
            int h = h0 + (G) * 4 + u;                                           \
            float acca = 0.f, accb = 0.f;                                       \
            _Pragma("unroll") for (int t = 0; t < 19; ++t) {                    \
                acca += F_G0[t] * Aa[t]; accb += F_G0[t] * Ab[t];               \
            }                                                                   \
            _Pragma("unroll") for (int t = 0; t < 13; ++t) {                    \
                acca += F_G1[t] * Ba[t]; accb += F_G1[t] * Bb[t];               \
            }                                                                   \
            *(unsigned*)(outp + base + h * st) = packbf(acca, accb);            \
            _Pragma("unroll") for (int t = 0; t < 18; ++t) {                    \
                Aa[t] = Aa[t + 1]; Ab[t] = Ab[t + 1];                           \
            }                                                                   \
            _Pragma("unroll") for (int t = 0; t < 12; ++t) {                    \
                Ba[t] = Ba[t + 1]; Bb[t] = Bb[t + 1];                           \
            }                                                                   \
            Aa[18] = bA[u].x; Ab[18] = bA[u].y;                                 \
            Ba[12] = bB[u].x; Bb[12] = bB[u].y;                                 \
        }                                                                       \
    }
    LDG(pa0, pb0, 0) LDG(pa1, pb1, 1)
    CPG(pa0, pb0, 0) LDG(pa0, pb0, 2)
    CPG(pa1, pb1, 1) LDG(pa1, pb1, 3)
    CPG(pa0, pb0, 2) LDG(pa0, pb0, 4)
    CPG(pa1, pb1, 3) LDG(pa1, pb1, 5)
    CPG(pa0, pb0, 4) LDG(pa0, pb0, 6)
    CPG(pa1, pb1, 5)
    CPG(pa0, pb0, 6)
#undef LDG
#undef CPG
}

__global__ __launch_bounds__(256) void k_inv_cols(
    const float* __restrict__ xl, const unsigned short* __restrict__ P0,
    const unsigned short* __restrict__ P1, const unsigned short* __restrict__ P2,
    unsigned short* __restrict__ lo2, unsigned short* __restrict__ hi2) {
    if (blockIdx.z == 0)
        inv_cols_body<0>(xl, P0, P1, P2, lo2, hi2);
    else
        inv_cols_body<1>(xl, P0, P1, P2, lo2, hi2);
}

// ---- K5: inverse row filters (bf16 in) -> out (fp32), 2ch/thread, batched
__global__ __launch_bounds__(256) void k_inv_rows(
    const unsigned short* __restrict__ lo2,
    const unsigned short* __restrict__ hi2, float* __restrict__ out) {
    int b = blockIdx.x / HS, h = blockIdx.x % HS;
    int strip = threadIdx.x >> 5;        // 0..7 strips of 7 w
    int c0 = (threadIdx.x & 31) * 2;
    int base = (b * HS + h) * WS * CH + c0;
    const unsigned short* rlo = lo2 + base;
    const unsigned short* rhi = hi2 + base;
    float* op = out + base;
    int w0s = strip * 7;
    float Aa[19], Ab[19], Ba[13], Bb[13];
#pragma unroll
    for (int t = 0; t < 19; ++t) {
        float2 v = bfp2(*(const unsigned*)(rlo + symi(w0s - 9 + t) * CH));
        Aa[t] = v.x; Ab[t] = v.y;
    }
#pragma unroll
    for (int t = 0; t < 13; ++t) {
        float2 v = bfp2(*(const unsigned*)(rhi + symi(w0s - 6 + t) * CH));
        Ba[t] = v.x; Bb[t] = v.y;
    }
    float2 nA[7], nB[7];
#pragma unroll
    for (int u = 0; u < 7; ++u) nA[u] = bfp2(*(const unsigned*)(rlo + symi(w0s + u + 10) * CH));
#pragma unroll
    for (int u = 0; u < 7; ++u) nB[u] = bfp2(*(const unsigned*)(rhi + symi(w0s + u + 7) * CH));
#pragma unroll
    for (int u = 0; u < 7; ++u) {
        int w = w0s + u;
        float acca = 0.f, accb = 0.f;
#pragma unroll
        for (int t = 0; t < 19; ++t) { acca += F_G0[t] * Aa[t]; accb += F_G0[t] * Ab[t]; }
#pragma unroll
        for (int t = 0; t < 13; ++t) { acca += F_G1[t] * Ba[t]; accb += F_G1[t] * Bb[t]; }
        float2 ov; ov.x = acca; ov.y = accb;
        *(float2*)(op + w * CH) = ov;
#pragma unroll
        for (int t = 0; t < 18; ++t) { Aa[t] = Aa[t + 1]; Ab[t] = Ab[t + 1]; }
#pragma unroll
        for (int t = 0; t < 12; ++t) { Ba[t] = Ba[t + 1]; Bb[t] = Bb[t + 1]; }
        Aa[18] = nA[u].x; Ab[18] = nA[u].y;
        Ba[12] = nB[u].x; Bb[12] = nB[u].y;
    }
}

extern "C" void kernel_launch(void* const* d_in, const int* in_sizes, int n_in,
                              void* d_out, int out_size, void* d_ws, size_t ws_size,
                              hipStream_t stream) {
    const float* x = (const float*)d_in[0];
    const float* w_ll = (const float*)d_in[1];
    const float* w1 = (const float*)d_in[2];
    const float* w2 = (const float*)d_in[3];
    const float* b1 = (const float*)d_in[4];
    const float* b2 = (const float*)d_in[5];
    float* out = (float*)d_out;

    // workspace map (float units). A = 6,422,528; SBf = 9,633,792.
    // xl | sbT(->lo2 bf16) | hi2 bf16 | lo_in | hi_in | P0 | P1 | P2
    const size_t A = (size_t)BT * HS * WS * CH;
    const size_t SBf = (size_t)12 * 64 * BT * PPOS / 2;
    float* wsf = (float*)d_ws;
    float* xl = wsf;                                    // fp32, read by inv mode0
    unsigned short* sbT = (unsigned short*)(wsf + A);   // dead after mix
    unsigned short* lo2 = (unsigned short*)(wsf + A);   //   .. reuses sbT region
    unsigned short* hi2 = (unsigned short*)(wsf + A + SBf);
    unsigned short* lo_in = (unsigned short*)(wsf + A + SBf + A);
    unsigned short* hi_in = lo_in + A;                  // bf16
    unsigned short* P0 = hi_in + A;                     // bf16
    unsigned short* P1 = P0 + A;
    unsigned short* P2 = P1 + A;

    float* wllT = out;  // staged in d_out head (overwritten by k_inv_rows)

    k_fwd_rows<<<BT * HS, 256, 0, stream>>>(x, lo_in, hi_in, w_ll, wllT);
    k_cols<<<dim3(BT * WH, 2, 2), 256, 0, stream>>>(lo_in, hi_in, wllT, xl, sbT);
    k_mix<<<3 * BT * 7, 256, 0, stream>>>(sbT, w1, w2, b1, b2, P0, P1, P2);
    k_inv_cols<<<dim3(BT * 7, 2, 2), 256, 0, stream>>>(xl, P0, P1, P2, lo2, hi2);
    k_inv_rows<<<BT * HS, 256, 0, stream>>>(lo2, hi2, out);
}

// Round 8
// 165.229 us; speedup vs baseline: 1.3249x; 1.0468x over previous
//
#include <hip/hip_runtime.h>

#define BT 32
#define CH 64
#define HS 56
#define WS 56
#define HH 28
#define WH 28

// ---------------- filter constants (exact reference values) ----------------
namespace {
constexpr float ISQ2 = 0.70710678118654752440f;
constexpr float F_H0[13] = {-0.0017578125f, 0.0f, 0.022265625f, -0.046875f,
    -0.0482421875f, 0.296875f, 0.55546875f, 0.296875f, -0.0482421875f,
    -0.046875f, 0.022265625f, 0.0f, -0.0017578125f};
constexpr float F_H1[19] = {-7.0626e-05f, 0.0f, 0.00134189f, -0.00188341f,
    -0.0071566f, 0.023856f, 0.0556431f, -0.0516881f, -0.299758f, 0.559431f,
    -0.299758f, -0.0516881f, 0.0556431f, 0.023856f, -0.0071566f,
    -0.00188341f, 0.00134189f, 0.0f, -7.0626e-05f};
constexpr float F_G0[19] = {7.0626e-05f, 0.0f, -0.00134189f, -0.00188341f,
    0.0071566f, 0.023856f, -0.0556431f, -0.0516881f, 0.299758f, 0.559431f,
    0.299758f, -0.0516881f, -0.0556431f, 0.023856f, 0.0071566f,
    -0.00188341f, -0.00134189f, 0.0f, 7.0626e-05f};
constexpr float F_G1[13] = {-0.0017578125f, 0.0f, 0.022265625f, 0.046875f,
    -0.0482421875f, -0.296875f, 0.55546875f, -0.296875f, -0.0482421875f,
    0.046875f, 0.022265625f, 0.0f, -0.0017578125f};
}

__device__ __forceinline__ int symi(int k) {
    k = (k < 0) ? (-1 - k) : k;
    k = (k >= HS) ? (2 * HS - 1 - k) : k;
    return k;
}

__device__ __forceinline__ unsigned short f2bf(float f) {  // RNE bf16
    unsigned u = __float_as_uint(f);
    u += 0x7fffu + ((u >> 16) & 1u);
    return (unsigned short)(u >> 16);
}
__device__ __forceinline__ float bf2f(unsigned short h) {
    return __uint_as_float(((unsigned)h) << 16);
}
// unpack 2 packed bf16 (channels c0, c0+1) from one dword
__device__ __forceinline__ float2 bfp2(unsigned u) {
    float2 r;
    r.x = __uint_as_float((u & 0xffffu) << 16);
    r.y = __uint_as_float(u & 0xffff0000u);
    return r;
}
__device__ __forceinline__ unsigned packbf(float a, float b) {
    return (unsigned)f2bf(a) | ((unsigned)f2bf(b) << 16);
}

typedef __attribute__((ext_vector_type(8))) short short8;  // 8 bf16 (4 VGPR)
typedef __attribute__((ext_vector_type(4))) float f32x4;

// sbT layout: [p 12][b 32][pos 784][c 64], bf16.
#define PPOS 784

// ---- K1: forward row filters: x -> lo, hi (bf16).
// Blocks 0..48 additionally transpose w_ll -> wllT (folds old k_wll_T launch).
__global__ __launch_bounds__(256) void k_fwd_rows(const float* __restrict__ x,
                                                  unsigned short* __restrict__ lo,
                                                  unsigned short* __restrict__ hi,
                                                  const float* __restrict__ wll,
                                                  float* __restrict__ wllT) {
    int b = blockIdx.x / HS, h = blockIdx.x % HS;
    int strip = threadIdx.x >> 5;        // 0..7 strips of 7 w
    int c0 = (threadIdx.x & 31) * 2;
    int base = (b * HS + h) * WS * CH + c0;
    const float* row = x + base;
    unsigned short* lop = lo + base;
    unsigned short* hip = hi + base;
    int w0s = strip * 7;
    float Wa[19], Wb[19];
#pragma unroll
    for (int t = 0; t < 19; ++t) {
        float2 v = *(const float2*)(row + symi(w0s - 9 + t) * CH);
        Wa[t] = v.x; Wb[t] = v.y;
    }
    float2 nW[7];
#pragma unroll
    for (int u = 0; u < 7; ++u) nW[u] = *(const float2*)(row + symi(w0s + u + 10) * CH);
#pragma unroll
    for (int u = 0; u < 7; ++u) {
        int w = w0s + u;
        float aLo = 0.f, aHi = 0.f, bLo = 0.f, bHi = 0.f;
#pragma unroll
        for (int t = 0; t < 13; ++t) { aLo += F_H0[t] * Wa[3 + t]; bLo += F_H0[t] * Wb[3 + t]; }
#pragma unroll
        for (int t = 0; t < 19; ++t) { aHi += F_H1[t] * Wa[t]; bHi += F_H1[t] * Wb[t]; }
        *(unsigned*)(lop + w * CH) = packbf(aLo, bLo);
        *(unsigned*)(hip + w * CH) = packbf(aHi, bHi);
#pragma unroll
        for (int t = 0; t < 18; ++t) { Wa[t] = Wa[t + 1]; Wb[t] = Wb[t + 1]; }
        Wa[18] = nW[u].x; Wb[18] = nW[u].y;
    }
    // ---- folded w_ll transpose (uniform per-block branch; 49 blocks) ----
    if (blockIdx.x < 49) {
        __shared__ float tile[64][65];
        int pos0 = blockIdx.x * 64;
        int lp = threadIdx.x & 63, g = threadIdx.x >> 6;
#pragma unroll
        for (int r = 0; r < 16; ++r) {
            int cc = r * 4 + g;
            tile[cc][lp] = wll[cc * (HS * WS) + pos0 + lp];
        }
        __syncthreads();
#pragma unroll
        for (int r = 0; r < 16; ++r) {
            int pl = r * 4 + g;
            wllT[(pos0 + pl) * CH + lp] = tile[lp][pl];
        }
    }
}

// ---- K2: merged column filters (z=0: lo path, z=1: hi path), hf=2 halves.
// xl output now bf16 (scalar ushort stores).
__global__ __launch_bounds__(256) void k_cols(
    const unsigned short* __restrict__ lo_in,
    const unsigned short* __restrict__ hi_in, const float* __restrict__ wllT,
    unsigned short* __restrict__ xl, unsigned short* __restrict__ sbT) {
    __shared__ float qT[2][4][64][15];  // 30.7 KB; lo path uses qT[0] only
    int hf = blockIdx.y;
    int zmode = blockIdx.z;            // uniform branch
    int b = blockIdx.x / WH, wp = blockIdx.x % WH;
    int w0 = 2 * wp, tid = threadIdx.x;
    int q = tid >> 6, c = tid & 63;
    int rp = q >> 1, jc = q & 1;
    const unsigned short* srcp = zmode ? hi_in : lo_in;
    const unsigned short* colbase = srcp + (b * HS) * WS * CH + (w0 + jc) * CH + c;
    {
        int hstart = 2 * (hf * 14) + rp;
        float W[19];
#pragma unroll
        for (int t = 0; t < 19; ++t) W[t] = bf2f(colbase[symi(hstart - 9 + t) * (WS * CH)]);
        float nW0[14], nW1[14], nwll[14];
#pragma unroll
        for (int u = 0; u < 14; ++u) {
            int h = hstart + 2 * u;
            nW0[u] = bf2f(colbase[symi(h + 10) * (WS * CH)]);
            nW1[u] = bf2f(colbase[symi(h + 11) * (WS * CH)]);
        }
        if (zmode == 0) {
#pragma unroll
            for (int u = 0; u < 14; ++u)
                nwll[u] = wllT[((hstart + 2 * u) * WS + (w0 + jc)) * CH + c];
        }
#pragma unroll
        for (int u = 0; u < 14; ++u) {
            int h = hstart + 2 * u;
            float v0 = 0.f, v1 = 0.f;
#pragma unroll
            for (int t = 0; t < 13; ++t) v0 += F_H0[t] * W[3 + t];
#pragma unroll
            for (int t = 0; t < 19; ++t) v1 += F_H1[t] * W[t];
            if (zmode == 0) {
                xl[((b * HS + h) * WS + (w0 + jc)) * CH + c] = f2bf(v0 * nwll[u]);
                qT[0][q][c][u] = v1;
            } else {
                qT[0][q][c][u] = v0;   // hl
                qT[1][q][c][u] = v1;   // hh
            }
#pragma unroll
            for (int t = 0; t < 17; ++t) W[t] = W[t + 2];
            W[17] = nW0[u];
            W[18] = nW1[u];
        }
    }
    __syncthreads();
    // fused q2c + bf16 pack: role 0:(a-d) 1:(b+c) 2:(a+d) 3:(b-c)
    {
        int qq = tid >> 5;                 // 0..7
        int role = qq & 3, half = qq >> 2; // ii 0..6 / 7..13
        int c0 = (tid & 31) * 2;
        int rowA = role & 1, rowB = 3 - (role & 1);
        float sgn = (role == 1 || role == 2) ? 1.f : -1.f;
        int posb = wp * 28 + hf * 14;
        if (zmode == 0) {
            int p = (role < 2) ? role : role + 8;  // planes 0,1,10,11
            const float* qA0 = &qT[0][rowA][c0][0];
            const float* qA1 = &qT[0][rowA][c0 + 1][0];
            const float* qB0 = &qT[0][rowB][c0][0];
            const float* qB1 = &qT[0][rowB][c0 + 1][0];
            unsigned short* dst = sbT + ((p * BT + b) * PPOS + posb) * CH + c0;
#pragma unroll
            for (int g = 0; g < 7; ++g) {
                int ii = half * 7 + g;
                float v0 = (qA0[ii] + sgn * qB0[ii]) * ISQ2;
                float v1 = (qA1[ii] + sgn * qB1[ii]) * ISQ2;
                *(unsigned*)(dst + ii * CH) = packbf(v0, v1);
            }
        } else {
#pragma unroll
            for (int src = 0; src < 2; ++src) {
                // src0 (hl): planes 4..7; src1 (hh): planes 2,3,8,9
                int p = (src == 0) ? (4 + role) : ((role < 2) ? (2 + role) : (6 + role));
                const float* qA0 = &qT[src][rowA][c0][0];
                const float* qA1 = &qT[src][rowA][c0 + 1][0];
                const float* qB0 = &qT[src][rowB][c0][0];
                const float* qB1 = &qT[src][rowB][c0 + 1][0];
                unsigned short* dst = sbT + ((p * BT + b) * PPOS + posb) * CH + c0;
#pragma unroll
                for (int g = 0; g < 7; ++g) {
                    int ii = half * 7 + g;
                    float v0 = (qA0[ii] + sgn * qB0[ii]) * ISQ2;
                    float v1 = (qA1[ii] + sgn * qB1[ii]) * ISQ2;
                    *(unsigned*)(dst + ii * CH) = packbf(v0, v1);
                }
            }
        }
    }
}

// ---- K3: MFMA channel mixing + fused c2q -> bf16 planes P[b][h][w][c]
// One 16-pos tile per block (chunk=1): grid 3*BT*49 = 4704 blocks for
// occupancy; 4-wave blocks (wv = nb).
__global__ __launch_bounds__(256) void k_mix(
    const unsigned short* __restrict__ sbT, const float* __restrict__ w1,
    const float* __restrict__ w2, const float* __restrict__ b1,
    const float* __restrict__ b2, unsigned short* __restrict__ P0,
    unsigned short* __restrict__ P1, unsigned short* __restrict__ P2) {
    __shared__ unsigned short l1a[4][16][36];
    __shared__ unsigned short l1b[4][16][36];
    int blk = blockIdx.x;
    int pr = blk / (BT * 49);
    int rem = blk % (BT * 49);
    int b = rem / 49;
    int tile = rem % 49;
    int sa = (pr == 0) ? 0 : (pr == 1) ? 2 : 1;
    int sb = (pr == 0) ? 5 : (pr == 1) ? 3 : 4;
    unsigned short* Pd = (pr == 0) ? P0 : (pr == 1) ? P1 : P2;
    int tid = threadIdx.x;
    int lane = tid & 63;
    int wv = tid >> 6;
    int nb = __builtin_amdgcn_readfirstlane(wv);
    int quad = lane >> 4;
    int n = lane & 15;

    // A-fragment loads issued FIRST (hide under weight-load chain)
    int rix = quad >> 1, dlo = (quad & 1) * 8;
    int pos0 = tile * 16;
    const unsigned short* pAa =
        sbT + (((sa * 2 + rix) * BT + b) * PPOS + pos0 + n) * CH + nb * 16 + dlo;
    const unsigned short* pAb =
        sbT + (((sb * 2 + rix) * BT + b) * PPOS + pos0 + n) * CH + nb * 16 + dlo;
    short8 A1a = *(const short8*)pAa;
    short8 A1b = *(const short8*)pAb;

    short8 B1r, B1i, B2r, B2i;
#pragma unroll
    for (int j = 0; j < 8; ++j) {
        int kk = quad * 8 + j;
        int riw = kk >> 4, dd = kk & 15;
        float v1r = w1[nb * 256 + dd * 16 + n];
        float v1i = w1[1024 + nb * 256 + dd * 16 + n];
        float v2r = w2[nb * 256 + dd * 16 + n];
        float v2i = w2[1024 + nb * 256 + dd * 16 + n];
        B1r[j] = (short)f2bf(riw ? -v1i : v1r);
        B1i[j] = (short)f2bf(riw ? v1r : v1i);
        B2r[j] = (short)f2bf(riw ? -v2i : v2r);
        B2i[j] = (short)f2bf(riw ? v2r : v2i);
    }
    float bias1r = b1[nb * 16 + n], bias1i = b1[64 + nb * 16 + n];
    float bias2r = b2[nb * 16 + n], bias2i = b2[64 + nb * 16 + n];

    f32x4 a1r = {bias1r, bias1r, bias1r, bias1r};
    f32x4 a1i = {bias1i, bias1i, bias1i, bias1i};
    f32x4 b1r_ = a1r, b1i_ = a1i;
    a1r = __builtin_amdgcn_mfma_f32_16x16x32_bf16(A1a, B1r, a1r, 0, 0, 0);
    a1i = __builtin_amdgcn_mfma_f32_16x16x32_bf16(A1a, B1i, a1i, 0, 0, 0);
    b1r_ = __builtin_amdgcn_mfma_f32_16x16x32_bf16(A1b, B1r, b1r_, 0, 0, 0);
    b1i_ = __builtin_amdgcn_mfma_f32_16x16x32_bf16(A1b, B1i, b1i_, 0, 0, 0);
#pragma unroll
    for (int r = 0; r < 4; ++r) {
        int pos = quad * 4 + r;
        l1a[wv][pos][n] = f2bf(fmaxf(a1r[r], 0.f));
        l1a[wv][pos][16 + n] = f2bf(fmaxf(a1i[r], 0.f));
        l1b[wv][pos][n] = f2bf(fmaxf(b1r_[r], 0.f));
        l1b[wv][pos][16 + n] = f2bf(fmaxf(b1i_[r], 0.f));
    }
    union { short8 s8; uint2 u2[2]; } a2a, a2b;
    const unsigned short* rowpa = &l1a[wv][n][0];
    const unsigned short* rowpb = &l1b[wv][n][0];
    a2a.u2[0] = *(const uint2*)(rowpa + quad * 8);
    a2a.u2[1] = *(const uint2*)(rowpa + quad * 8 + 4);
    a2b.u2[0] = *(const uint2*)(rowpb + quad * 8);
    a2b.u2[1] = *(const uint2*)(rowpb + quad * 8 + 4);
    f32x4 aAr = {bias2r, bias2r, bias2r, bias2r};
    f32x4 aAi = {bias2i, bias2i, bias2i, bias2i};
    f32x4 aBr = aAr, aBi = aAi;
    aAr = __builtin_amdgcn_mfma_f32_16x16x32_bf16(a2a.s8, B2r, aAr, 0, 0, 0);
    aAi = __builtin_amdgcn_mfma_f32_16x16x32_bf16(a2a.s8, B2i, aAi, 0, 0, 0);
    aBr = __builtin_amdgcn_mfma_f32_16x16x32_bf16(a2b.s8, B2r, aBr, 0, 0, 0);
    aBi = __builtin_amdgcn_mfma_f32_16x16x32_bf16(a2b.s8, B2i, aBi, 0, 0, 0);
#pragma unroll
    for (int r = 0; r < 4; ++r) {
        int pos_g = pos0 + quad * 4 + r;
        int wp = pos_g / 28, ii = pos_g - wp * 28;
        int o = ((b * HS + 2 * ii) * WS + 2 * wp) * CH + nb * 16 + n;
        Pd[o] = f2bf((aAr[r] + aBr[r]) * ISQ2);
        Pd[o + CH] = f2bf((aAi[r] + aBi[r]) * ISQ2);
        Pd[o + WS * CH] = f2bf((aAi[r] - aBi[r]) * ISQ2);
        Pd[o + WS * CH + CH] = f2bf((aBr[r] - aAr[r]) * ISQ2);
    }
}

// ---- K4: inverse column pass, templated on mode (uniform blockIdx.z):
//   MODE=0: lo2 = G0col(xl bf16) + G1col(P0);  MODE=1: hi2 = G0col(P1) + G1col(P2)
// Outputs lo2/hi2 bf16. 2-deep software-pipelined groups of 4.
template <int MODE>
__device__ __forceinline__ void inv_cols_body(
    const unsigned short* __restrict__ xl, const unsigned short* __restrict__ P0,
    const unsigned short* __restrict__ P1, const unsigned short* __restrict__ P2,
    unsigned short* __restrict__ lo2, unsigned short* __restrict__ hi2) {
    int hf = blockIdx.y;
    int b = blockIdx.x / 7, wg = blockIdx.x % 7;
    int wl = threadIdx.x >> 5, l = threadIdx.x & 31;
    int c0 = l * 2;
    int w = wg * 8 + wl;
    int base = (b * HS) * WS * CH + w * CH + c0;
    const int st = WS * CH;
    const unsigned short* Ap = (MODE == 0) ? xl : P1;
    const unsigned short* Bp = (MODE == 0) ? P0 : P2;
    unsigned short* outp = (MODE == 0) ? lo2 : hi2;
    auto ldA = [&](int r) -> float2 {
        return bfp2(*(const unsigned*)(Ap + base + r * st));
    };
    auto ldB = [&](int r) -> float2 {
        return bfp2(*(const unsigned*)(Bp + base + r * st));
    };
    int h0 = hf * 28;
    float Aa[19], Ab[19], Ba[13], Bb[13];
#pragma unroll
    for (int t = 0; t < 19; ++t) { float2 v = ldA(symi(h0 - 9 + t)); Aa[t] = v.x; Ab[t] = v.y; }
#pragma unroll
    for (int t = 0; t < 13; ++t) { float2 v = ldB(symi(h0 - 6 + t)); Ba[t] = v.x; Bb[t] = v.y; }
    float2 pa0[4], pb0[4], pa1[4], pb1[4];
#define LDG(bA, bB, G)                                                          \
    {                                                                           \
        _Pragma("unroll") for (int u = 0; u < 4; ++u)                           \
            bA[u] = ldA(symi(h0 + (G) * 4 + u + 10));                           \
        _Pragma("unroll") for (int u = 0; u < 4; ++u)                           \
            bB[u] = ldB(symi(h0 + (G) * 4 + u + 7));                            \
    }
#define CPG(bA, bB, G)                                                          \
    {                                                                           \
        _Pragma("unroll") for (int u = 0; u < 4; ++u) {                         \
            int h = h0 + (G) * 4 + u;                                           \
            float acca = 0.f, accb = 0.f;                                       \
            _Pragma("unroll") for (int t = 0; t < 19; ++t) {                    \
                acca += F_G0[t] * Aa[t]; accb += F_G0[t] * Ab[t];               \
            }                                                                   \
            _Pragma("unroll") for (int t = 0; t < 13; ++t) {                    \
                acca += F_G1[t] * Ba[t]; accb += F_G1[t] * Bb[t];               \
            }                                                                   \
            *(unsigned*)(outp + base + h * st) = packbf(acca, accb);            \
            _Pragma("unroll") for (int t = 0; t < 18; ++t) {                    \
                Aa[t] = Aa[t + 1]; Ab[t] = Ab[t + 1];                           \
            }                                                                   \
            _Pragma("unroll") for (int t = 0; t < 12; ++t) {                    \
                Ba[t] = Ba[t + 1]; Bb[t] = Bb[t + 1];                           \
            }                                                                   \
            Aa[18] = bA[u].x; Ab[18] = bA[u].y;                                 \
            Ba[12] = bB[u].x; Bb[12] = bB[u].y;                                 \
        }                                                                       \
    }
    LDG(pa0, pb0, 0) LDG(pa1, pb1, 1)
    CPG(pa0, pb0, 0) LDG(pa0, pb0, 2)
    CPG(pa1, pb1, 1) LDG(pa1, pb1, 3)
    CPG(pa0, pb0, 2) LDG(pa0, pb0, 4)
    CPG(pa1, pb1, 3) LDG(pa1, pb1, 5)
    CPG(pa0, pb0, 4) LDG(pa0, pb0, 6)
    CPG(pa1, pb1, 5)
    CPG(pa0, pb0, 6)
#undef LDG
#undef CPG
}

__global__ __launch_bounds__(256) void k_inv_cols(
    const unsigned short* __restrict__ xl, const unsigned short* __restrict__ P0,
    const unsigned short* __restrict__ P1, const unsigned short* __restrict__ P2,
    unsigned short* __restrict__ lo2, unsigned short* __restrict__ hi2) {
    if (blockIdx.z == 0)
        inv_cols_body<0>(xl, P0, P1, P2, lo2, hi2);
    else
        inv_cols_body<1>(xl, P0, P1, P2, lo2, hi2);
}

// ---- K5: inverse row filters (bf16 in) -> out (fp32), 2ch/thread, batched
__global__ __launch_bounds__(256) void k_inv_rows(
    const unsigned short* __restrict__ lo2,
    const unsigned short* __restrict__ hi2, float* __restrict__ out) {
    int b = blockIdx.x / HS, h = blockIdx.x % HS;
    int strip = threadIdx.x >> 5;        // 0..7 strips of 7 w
    int c0 = (threadIdx.x & 31) * 2;
    int base = (b * HS + h) * WS * CH + c0;
    const unsigned short* rlo = lo2 + base;
    const unsigned short* rhi = hi2 + base;
    float* op = out + base;
    int w0s = strip * 7;
    float Aa[19], Ab[19], Ba[13], Bb[13];
#pragma unroll
    for (int t = 0; t < 19; ++t) {
        float2 v = bfp2(*(const unsigned*)(rlo + symi(w0s - 9 + t) * CH));
        Aa[t] = v.x; Ab[t] = v.y;
    }
#pragma unroll
    for (int t = 0; t < 13; ++t) {
        float2 v = bfp2(*(const unsigned*)(rhi + symi(w0s - 6 + t) * CH));
        Ba[t] = v.x; Bb[t] = v.y;
    }
    float2 nA[7], nB[7];
#pragma unroll
    for (int u = 0; u < 7; ++u) nA[u] = bfp2(*(const unsigned*)(rlo + symi(w0s + u + 10) * CH));
#pragma unroll
    for (int u = 0; u < 7; ++u) nB[u] = bfp2(*(const unsigned*)(rhi + symi(w0s + u + 7) * CH));
#pragma unroll
    for (int u = 0; u < 7; ++u) {
        int w = w0s + u;
        float acca = 0.f, accb = 0.f;
#pragma unroll
        for (int t = 0; t < 19; ++t) { acca += F_G0[t] * Aa[t]; accb += F_G0[t] * Ab[t]; }
#pragma unroll
        for (int t = 0; t < 13; ++t) { acca += F_G1[t] * Ba[t]; accb += F_G1[t] * Bb[t]; }
        float2 ov; ov.x = acca; ov.y = accb;
        *(float2*)(op + w * CH) = ov;
#pragma unroll
        for (int t = 0; t < 18; ++t) { Aa[t] = Aa[t + 1]; Ab[t] = Ab[t + 1]; }
#pragma unroll
        for (int t = 0; t < 12; ++t) { Ba[t] = Ba[t + 1]; Bb[t] = Bb[t + 1]; }
        Aa[18] = nA[u].x; Ab[18] = nA[u].y;
        Ba[12] = nB[u].x; Bb[12] = nB[u].y;
    }
}

extern "C" void kernel_launch(void* const* d_in, const int* in_sizes, int n_in,
                              void* d_out, int out_size, void* d_ws, size_t ws_size,
                              hipStream_t stream) {
    const float* x = (const float*)d_in[0];
    const float* w_ll = (const float*)d_in[1];
    const float* w1 = (const float*)d_in[2];
    const float* w2 = (const float*)d_in[3];
    const float* b1 = (const float*)d_in[4];
    const float* b2 = (const float*)d_in[5];
    float* out = (float*)d_out;

    // workspace map (float units). A = 6,422,528; SBf = 9,633,792.
    // xl(bf16, region A) | sbT(->lo2 bf16) | hi2 bf16 | lo_in | hi_in | P0|P1|P2
    const size_t A = (size_t)BT * HS * WS * CH;
    const size_t SBf = (size_t)12 * 64 * BT * PPOS / 2;
    float* wsf = (float*)d_ws;
    unsigned short* xl = (unsigned short*)wsf;          // bf16 (region oversized)
    unsigned short* sbT = (unsigned short*)(wsf + A);   // dead after mix
    unsigned short* lo2 = (unsigned short*)(wsf + A);   //   .. reuses sbT region
    unsigned short* hi2 = (unsigned short*)(wsf + A + SBf);
    unsigned short* lo_in = (unsigned short*)(wsf + A + SBf + A);
    unsigned short* hi_in = lo_in + A;                  // bf16
    unsigned short* P0 = hi_in + A;                     // bf16
    unsigned short* P1 = P0 + A;
    unsigned short* P2 = P1 + A;

    float* wllT = out;  // staged in d_out head (overwritten by k_inv_rows)

    k_fwd_rows<<<BT * HS, 256, 0, stream>>>(x, lo_in, hi_in, w_ll, wllT);
    k_cols<<<dim3(BT * WH, 2, 2), 256, 0, stream>>>(lo_in, hi_in, wllT, xl, sbT);
    k_mix<<<3 * BT * 49, 256, 0, stream>>>(sbT, w1, w2, b1, b2, P0, P1, P2);
    k_inv_cols<<<dim3(BT * 7, 2, 2), 256, 0, stream>>>(xl, P0, P1, P2, lo2, hi2);
    k_inv_rows<<<BT * HS, 256, 0, stream>>>(lo2, hi2, out);
}